// Round 3
// baseline (425.319 us; speedup 1.0000x reference)
//
#include <hip/hip_runtime.h>

#define DELTA 1e-6f

// sizes: b=64, m=1024, w=64, r=4, d=512, iface=471
#define NB 64
#define NM 1024
#define NW 64
#define NR 4
#define ND 512
#define NIF 471
#define CTILE 256
#define RTILE 256

__device__ __forceinline__ float sigmoidf_(float x){ return 1.0f/(1.0f+expf(-x)); }
__device__ __forceinline__ float softplusf_(float x){ return fmaxf(x,0.0f) + log1pf(expf(-fabsf(x))); }

__device__ __forceinline__ float waveSum(float v){
  #pragma unroll
  for(int o=32;o>0;o>>=1) v += __shfl_down(v,o,64);
  return v;
}
__device__ __forceinline__ float waveMax(float v){
  #pragma unroll
  for(int o=32;o>0;o>>=1) v = fmaxf(v, __shfl_down(v,o,64));
  return v;
}
// DPP quad_perm xor-1 / xor-2 (VALU pipe, no LDS)
__device__ __forceinline__ float dpp_xor1(float x){
  int p = __builtin_amdgcn_update_dpp(0, __float_as_int(x), 0xB1, 0xF, 0xF, true);
  return __int_as_float(p);
}
__device__ __forceinline__ float dpp_xor2(float x){
  int p = __builtin_amdgcn_update_dpp(0, __float_as_int(x), 0x4E, 0xF, 0xF, true);
  return __int_as_float(p);
}

// ---------------- K1: iface = xi @ W + bW ----------------
__global__ __launch_bounds__(256) void k_iface(const float* __restrict__ xi,
                                               const float* __restrict__ Wm,
                                               const float* __restrict__ bW,
                                               float* __restrict__ iface){
  int b = blockIdx.x;
  __shared__ float xs[ND];
  for(int k=threadIdx.x;k<ND;k+=256) xs[k]=xi[b*ND+k];
  __syncthreads();
  for(int c=threadIdx.x;c<NIF;c+=256){
    float acc = bW[c];
    #pragma unroll 4
    for(int k=0;k<ND;k++) acc = fmaf(xs[k], Wm[k*NIF+c], acc);
    iface[b*NIF+c]=acc;
  }
}

// ---------------- K2: usage/psi, write-content softmax, allocation (sort), new_write_w ----------------
__global__ __launch_bounds__(1024) void k_write(
    const float* __restrict__ iface, const float* __restrict__ mem,
    const float* __restrict__ rw_old, const float* __restrict__ ww_old,
    const float* __restrict__ uv, float* __restrict__ wwp){
  int b = blockIdx.x; int tid = threadIdx.x;
  int lane = tid & 63, wv = tid >> 6;
  __shared__ float wkey[NW];
  __shared__ unsigned long long skey[NM];
  __shared__ float fb[NM];
  __shared__ float fb2[NM];
  __shared__ float red[17];
  const float* ifb = iface + b*NIF;
  if (tid < NW) wkey[tid] = ifb[260+tid];
  __syncthreads();
  float sw = softplusf_(1.0f + fmaxf(ifb[324],0.0f));
  float ag = sigmoidf_(ifb[457]);
  float wg = sigmoidf_(ifb[458]);
  float fg0=sigmoidf_(ifb[453]), fg1=sigmoidf_(ifb[454]);
  float fg2=sigmoidf_(ifb[455]), fg3=sigmoidf_(ifb[456]);
  float kn=0.0f;
  for(int k=0;k<NW;k++){ float t=wkey[k]; kn += t*t; }
  kn = sqrtf(kn);
  int j = tid;
  float u0  = uv[b*NM+j];
  float wwo = ww_old[b*NM+j];
  float usage = u0 + (1.0f-u0)*(1.0f - (1.0f-wwo));
  float psi = (1.0f - fg0*rw_old[(b*NR+0)*NM+j])
            * (1.0f - fg1*rw_old[(b*NR+1)*NM+j])
            * (1.0f - fg2*rw_old[(b*NR+2)*NM+j])
            * (1.0f - fg3*rw_old[(b*NR+3)*NM+j]);
  usage *= psi;
  float dot=0.0f, nrm=0.0f;
  const float* mrow = mem + ((size_t)b*NM + j)*NW;
  for(int k=0;k<NW;k++){ float mv=mrow[k]; dot = fmaf(mv,wkey[k],dot); nrm = fmaf(mv,mv,nrm); }
  float logit = sw * dot / ((sqrtf(nrm)+DELTA)*(kn+DELTA));
  float m1 = waveMax(logit); if(lane==0) red[wv]=m1; __syncthreads();
  if(tid==0){ float mm=red[0]; for(int i=1;i<16;i++) mm=fmaxf(mm,red[i]); red[16]=mm; } __syncthreads();
  float e = expf(logit - red[16]);
  float s1 = waveSum(e); if(lane==0) red[wv]=s1; __syncthreads();
  if(tid==0){ float ss=0; for(int i=0;i<16;i++) ss+=red[i]; red[16]=ss; } __syncthreads();
  float wcw = e/red[16];
  float u = DELTA + (1.0f-DELTA)*usage;
  skey[tid] = ((unsigned long long)__float_as_uint(u) << 32) | (unsigned)tid;
  __syncthreads();
  for(int k2=2;k2<=NM;k2<<=1){
    for(int jj=k2>>1;jj>0;jj>>=1){
      int ixj = tid ^ jj;
      if (ixj > tid){
        unsigned long long a=skey[tid], c=skey[ixj];
        bool asc = ((tid & k2)==0);
        bool doswap = asc ? (a>c) : (a<c);
        if (doswap){ skey[tid]=c; skey[ixj]=a; }
      }
      __syncthreads();
    }
  }
  float su = __uint_as_float((unsigned)(skey[tid]>>32));
  int phi  = (int)(skey[tid] & 0xffffffffu);
  fb[tid] = su; __syncthreads();
  for(int d=1; d<NM; d<<=1){
    float o = (tid>=d)? fb[tid-d] : 1.0f;
    __syncthreads();
    fb[tid] *= o;
    __syncthreads();
  }
  float salloc = (1.0f - su)*fb[tid];
  fb2[phi] = salloc;
  __syncthreads();
  float alloc = fb2[tid];
  wwp[b*NM+tid] = wg*(ag*alloc + (1.0f-ag)*wcw);
}

// ---------------- K3: one streaming pass over L ----------------
// Per block: 256 rows x 256 cols of L[b].
// Row sums  : RF[r,j] = sum_n L[j,n]*((1-ww[j])*rw[r,n] - ww[n]*rw[r,n])  (atomicAdd, 4 col-tiles)
// Col sums  : C2[r,n] = sum_m L[m,n]*rw[r,m];  C3[r,n] = sum_m L[m,n]*rw[r,m]*ww[m]  (atomicAdd, 4 row-tiles)
__global__ __launch_bounds__(256, 3) void k_link2(
    const float* __restrict__ link, const float* __restrict__ rw,
    const float* __restrict__ wwp,
    float* __restrict__ RF, float* __restrict__ C2, float* __restrict__ C3){
  int cx = blockIdx.x, ry = blockIdx.y, b = blockIdx.z;
  int tid = threadIdx.x, lane = tid&63, wv = tid>>6;
  __shared__ float s_gg[NR][RTILE];
  __shared__ float s_ww[RTILE];
  #pragma unroll
  for (int r=0;r<NR;r++) s_gg[r][tid] = rw[(b*NR+r)*NM + ry*RTILE + tid];
  s_ww[tid] = wwp[b*NM + ry*RTILE + tid];
  __syncthreads();
  int c0 = cx*CTILE + lane*4;
  // per-lane column weights (g = rw[r][col], h = g*ww[col])
  float g[NR][4], h[NR][4];
  float4 wwc4 = *(const float4*)(wwp + b*NM + c0);
  float wwc[4] = {wwc4.x, wwc4.y, wwc4.z, wwc4.w};
  #pragma unroll
  for (int r=0;r<NR;r++){
    float4 gv = *(const float4*)(rw + (b*NR+r)*NM + c0);
    g[r][0]=gv.x; g[r][1]=gv.y; g[r][2]=gv.z; g[r][3]=gv.w;
    #pragma unroll
    for (int e=0;e<4;e++) h[r][e] = g[r][e]*wwc[e];
  }
  float c2a[NR][4]={}, c3a[NR][4]={};
  const float* Lw = link + ((size_t)b<<20) + (size_t)(ry*RTILE + wv*64)*NM + c0;
  float4 Lbuf[4];
  #pragma unroll
  for (int rr=0;rr<4;rr++) Lbuf[rr] = *(const float4*)(Lw + (size_t)rr*NM);
  for (int grp=0; grp<16; ++grp){
    float4 Lcur[4];
    #pragma unroll
    for (int rr=0;rr<4;rr++) Lcur[rr]=Lbuf[rr];
    if (grp < 15){
      const float* Ln = Lw + (size_t)((grp+1)*4)*NM;
      #pragma unroll
      for (int rr=0;rr<4;rr++) Lbuf[rr] = *(const float4*)(Ln + (size_t)rr*NM);
    }
    int rl0 = wv*64 + grp*4;
    // v[row*8 + isB*4 + r]
    float v[32];
    #pragma unroll
    for (int i=0;i<32;i++) v[i]=0.0f;
    #pragma unroll
    for (int rr=0;rr<4;rr++){
      float le[4] = {Lcur[rr].x, Lcur[rr].y, Lcur[rr].z, Lcur[rr].w};
      float wwr = s_ww[rl0+rr];
      #pragma unroll
      for (int r=0;r<NR;r++){
        float ggr = s_gg[r][rl0+rr];
        float hhr = ggr*wwr;
        #pragma unroll
        for (int e=0;e<4;e++){
          c2a[r][e]   = fmaf(le[e], ggr,    c2a[r][e]);
          c3a[r][e]   = fmaf(le[e], hhr,    c3a[r][e]);
          v[rr*8+r]   = fmaf(le[e], g[r][e], v[rr*8+r]);
          v[rr*8+4+r] = fmaf(le[e], h[r][e], v[rr*8+4+r]);
        }
      }
    }
    // compact butterfly: lane ends with sum over lanes of v[lane&31]
    float w16[16];
    #pragma unroll
    for (int jj=0;jj<16;jj++){ w16[jj] = (lane&1)? v[2*jj+1] : v[2*jj]; }
    #pragma unroll
    for (int jj=0;jj<16;jj++) w16[jj] += dpp_xor1(w16[jj]);
    float w8[8];
    #pragma unroll
    for (int jj=0;jj<8;jj++){ w8[jj] = (lane&2)? w16[2*jj+1] : w16[2*jj]; }
    #pragma unroll
    for (int jj=0;jj<8;jj++) w8[jj] += dpp_xor2(w8[jj]);
    float w4a[4];
    #pragma unroll
    for (int jj=0;jj<4;jj++){ w4a[jj] = (lane&4)? w8[2*jj+1] : w8[2*jj]; }
    #pragma unroll
    for (int jj=0;jj<4;jj++) w4a[jj] += __shfl_xor(w4a[jj], 4, 64);
    float w2a[2];
    #pragma unroll
    for (int jj=0;jj<2;jj++){ w2a[jj] = (lane&8)? w4a[2*jj+1] : w4a[2*jj]; }
    #pragma unroll
    for (int jj=0;jj<2;jj++) w2a[jj] += __shfl_xor(w2a[jj], 8, 64);
    float w1 = (lane&16)? w2a[1] : w2a[0];
    w1 += __shfl_xor(w1, 16, 64);
    w1 += __shfl_xor(w1, 32, 64);
    float other = __shfl_xor(w1, 4, 64);   // partner has isB flipped
    int i5 = lane & 31;
    int rowIdx = i5>>3, which = i5&7, r_ = which&3, isB = which>>2;
    if (!isB && lane < 32){
      int rl = rl0 + rowIdx;
      float wwj = s_ww[rl];
      float rf = fmaf(-wwj, w1, w1) - other;   // (1-wwj)*SumA - SumB
      atomicAdd(&RF[(b*NR + r_)*NM + ry*RTILE + rl], rf);
    }
  }
  #pragma unroll
  for (int r=0;r<NR;r++){
    #pragma unroll
    for (int e=0;e<4;e++){
      atomicAdd(&C2[(b*NR+r)*NM + c0+e], c2a[r][e]);
      atomicAdd(&C3[(b*NR+r)*NM + c0+e], c3a[r][e]);
    }
  }
}

// ---------------- K4: read-content softmax, forward/backward finalize, read_vectors ----------------
__global__ __launch_bounds__(1024) void k_read(
    const float* __restrict__ iface, const float* __restrict__ mem,
    const float* __restrict__ link, const float* __restrict__ prec,
    const float* __restrict__ rw_old, const float* __restrict__ wwp,
    const float* __restrict__ RF,
    const float* __restrict__ C2, const float* __restrict__ C3,
    float* __restrict__ out){
  int b = blockIdx.x; int tid = threadIdx.x; int lane=tid&63, wv=tid>>6;
  __shared__ float keys[NR][NW];
  __shared__ float er[NW], wvec[NW];
  __shared__ float wwb[NM];
  __shared__ float nrw[NR][NM];
  __shared__ float red[17];
  __shared__ float scal[16];   // [0..3]=Pr, [4..7]=Kr, [8..11]=keynorm, [12..15]=strength
  __shared__ float rm[NR][3];
  __shared__ float accb[16][NR][NW];
  const float* ifb = iface + b*NIF;
  if (tid < 256){ int r=tid>>6, k=tid&63; keys[r][k] = ifb[r*NW+k]; }
  if (tid >= 256 && tid < 320){ int k=tid-256; er[k]=sigmoidf_(ifb[325+k]); wvec[k]=ifb[389+k]; }
  wwb[tid] = wwp[b*NM+tid];
  if (tid == 0){
    for(int mo=0;mo<3;mo++){
      float x0=ifb[458+0*3+mo], x1=ifb[458+1*3+mo], x2=ifb[458+2*3+mo], x3=ifb[458+3*3+mo];
      float mx = fmaxf(fmaxf(x0,x1),fmaxf(x2,x3));
      float e0=expf(x0-mx),e1=expf(x1-mx),e2=expf(x2-mx),e3=expf(x3-mx);
      float s=e0+e1+e2+e3;
      rm[0][mo]=e0/s; rm[1][mo]=e1/s; rm[2][mo]=e2/s; rm[3][mo]=e3/s;
    }
  }
  __syncthreads();
  if (tid < NR){
    float knv=0; for(int k=0;k<NW;k++){ float t=keys[tid][k]; knv += t*t; }
    scal[8+tid]  = sqrtf(knv);
    scal[12+tid] = softplusf_(1.0f + fmaxf(ifb[256+tid],0.0f));
  }
  int j = tid;
  float pj  = prec[b*NM+j];
  float wwj = wwb[j];
  float rwv[NR];
  #pragma unroll
  for(int r=0;r<NR;r++) rwv[r]=rw_old[(b*NR+r)*NM+j];
  for(int q=0;q<8;q++){
    float v = (q<4)? pj*rwv[q] : wwj*rwv[q-4];
    float s = waveSum(v);
    if(lane==0) red[wv]=s;
    __syncthreads();
    if(tid==0){ float ss=0; for(int i=0;i<16;i++) ss+=red[i]; scal[q]=ss; }
    __syncthreads();
  }
  const float* mrow = mem + ((size_t)b*NM+j)*NW;
  float dots[NR]={0,0,0,0}; float nrm=0.0f;
  for(int k=0;k<NW;k++){
    float nmv = fmaf(mrow[k], (1.0f - wwj*er[k]), wwj*wvec[k]);
    nrm = fmaf(nmv,nmv,nrm);
    #pragma unroll
    for(int r=0;r<NR;r++) dots[r] = fmaf(nmv, keys[r][k], dots[r]);
  }
  float inv = 1.0f/(sqrtf(nrm)+DELTA);
  float cw[NR];
  for(int r=0;r<NR;r++){
    float logit = scal[12+r]*dots[r]*inv/(scal[8+r]+DELTA);
    float m1 = waveMax(logit); if(lane==0) red[wv]=m1; __syncthreads();
    if(tid==0){ float mm=red[0]; for(int i=1;i<16;i++) mm=fmaxf(mm,red[i]); red[16]=mm; } __syncthreads();
    float e = expf(logit - red[16]);
    float s1 = waveSum(e); if(lane==0) red[wv]=s1; __syncthreads();
    if(tid==0){ float ss=0; for(int i=0;i<16;i++) ss+=red[i]; red[16]=ss; } __syncthreads();
    cw[r] = e/red[16];
    __syncthreads();
  }
  float Ljj = link[((size_t)b<<20) + (size_t)j*(NM+1)];
  #pragma unroll
  for(int r=0;r<NR;r++){
    float F  = RF[(b*NR+r)*NM+j];
    float cc2 = C2[(b*NR+r)*NM+j], cc3 = C3[(b*NR+r)*NM+j];
    float grj = rwv[r];
    float fwd = F - Ljj*grj*(1.0f-2.0f*wwj) + wwj*(scal[r] - pj*grj);
    float bwd = (cc2 - cc3) - Ljj*grj*(1.0f-wwj) - wwj*(cc2 - Ljj*grj) + pj*(scal[4+r] - wwj*grj);
    nrw[r][j] = rm[r][0]*bwd + rm[r][1]*fwd + rm[r][2]*cw[r];
  }
  __syncthreads();
  int w = lane;
  float erw = er[w], wvw = wvec[w];
  float acc[NR]={0,0,0,0};
  int jbase = wv*64;
  for(int jj=0;jj<64;jj++){
    int jr = jbase+jj;
    float wwr = wwb[jr];
    float nmv = fmaf(mem[((size_t)b*NM+jr)*NW + w], (1.0f - wwr*erw), wwr*wvw);
    #pragma unroll
    for(int r=0;r<NR;r++) acc[r] = fmaf(nrw[r][jr], nmv, acc[r]);
  }
  #pragma unroll
  for(int r=0;r<NR;r++) accb[wv][r][w] = acc[r];
  __syncthreads();
  if (tid < 256){
    int r = tid>>6, k = tid&63;
    float s=0;
    for(int v=0;v<16;v++) s += accb[v][r][k];
    out[b*NR*NW + r*NW + k] = s;
  }
}

extern "C" void kernel_launch(void* const* d_in, const int* in_sizes, int n_in,
                              void* d_out, int out_size, void* d_ws, size_t ws_size,
                              hipStream_t stream) {
  (void)in_sizes; (void)n_in; (void)out_size; (void)ws_size;
  const float* xi   = (const float*)d_in[0];
  const float* Wm   = (const float*)d_in[1];
  const float* bW   = (const float*)d_in[2];
  const float* mem  = (const float*)d_in[3];
  const float* link = (const float*)d_in[4];
  const float* prec = (const float*)d_in[5];
  const float* rw   = (const float*)d_in[6];
  const float* wwo  = (const float*)d_in[7];
  const float* uv   = (const float*)d_in[8];
  float* out = (float*)d_out;
  float* ws  = (float*)d_ws;
  float* iface = ws;                 // 64*471 -> pad 30208
  float* wwp   = ws + 30208;         // 65536
  float* RF    = wwp + 65536;        // 262144
  float* C2    = RF + 262144;        // 262144
  float* C3    = C2 + 262144;        // 262144
  hipMemsetAsync(RF, 0, 3*262144*sizeof(float), stream);  // RF,C2,C3
  k_iface<<<NB, 256, 0, stream>>>(xi, Wm, bW, iface);
  k_write<<<NB, 1024, 0, stream>>>(iface, mem, rw, wwo, uv, wwp);
  k_link2<<<dim3(4, 4, NB), 256, 0, stream>>>(link, rw, wwp, RF, C2, C3);
  k_read<<<NB, 1024, 0, stream>>>(iface, mem, link, prec, rw, wwp, RF, C2, C3, out);
}